// Round 4
// baseline (800.135 us; speedup 1.0000x reference)
//
#include <hip/hip_runtime.h>

#define D 128

// ---------------------------------------------------------------------------
// Fused dual GEMM: S1 = X @ W1, S2 = X @ W2.  X:[N,128] f32, W:[128,128].
// Block = 256 thr, tile BM=64 rows x BN=256 cols (cols 0..127 -> S1, 128..255 -> S2),
// BK=16. Per-thread 8x8 register tile. No MFMA (no fp32 MFMA on CDNA4).
// ---------------------------------------------------------------------------
__global__ __launch_bounds__(256) void gemm_dual(const float* __restrict__ X,
                                                 const float* __restrict__ W1,
                                                 const float* __restrict__ W2,
                                                 float* __restrict__ S1,
                                                 float* __restrict__ S2, int N)
{
    __shared__ float Xs[16][64];    // transposed: Xs[k][m]
    __shared__ float Ws[16][256];   // Ws[k][n]  (n<128 -> W1, n>=128 -> W2)

    const int tid = threadIdx.x;
    const int tx = tid & 31;   // col group 0..31 (4 cols per matrix)
    const int ty = tid >> 5;   // row group 0..7  (8 rows)
    const int row0 = blockIdx.x * 64;

    float acc[8][8];
#pragma unroll
    for (int m = 0; m < 8; ++m)
#pragma unroll
        for (int n = 0; n < 8; ++n) acc[m][n] = 0.f;

    // staging assignments
    const int xr = tid >> 2;          // 0..63 (row within tile)
    const int xk = (tid & 3) << 2;    // 0,4,8,12 (k offset)
    const int wk = tid >> 4;          // 0..15 (k within tile)
    const int seg = tid & 15;         // 0..15 (16-col segment)
    const float* wsrc = (seg < 8) ? W1 : W2;
    const int wc = (seg & 7) << 4;    // 0..112 source col
    const int wdst = ((seg < 8) ? 0 : 128) + wc;

    for (int k0 = 0; k0 < 128; k0 += 16) {
        // issue global loads first (overlap with previous LDS reads)
        float4 xv = make_float4(0.f, 0.f, 0.f, 0.f);
        const int grow = row0 + xr;
        if (grow < N) xv = *(const float4*)&X[(size_t)grow * D + k0 + xk];
        const float* wsp = &wsrc[(size_t)(k0 + wk) * D + wc];
        const float4 w0 = *(const float4*)(wsp + 0);
        const float4 w1 = *(const float4*)(wsp + 4);
        const float4 w2 = *(const float4*)(wsp + 8);
        const float4 w3 = *(const float4*)(wsp + 12);

        __syncthreads();   // previous iteration's LDS reads done
        Xs[xk + 0][xr] = xv.x;
        Xs[xk + 1][xr] = xv.y;
        Xs[xk + 2][xr] = xv.z;
        Xs[xk + 3][xr] = xv.w;
        *(float4*)&Ws[wk][wdst + 0]  = w0;
        *(float4*)&Ws[wk][wdst + 4]  = w1;
        *(float4*)&Ws[wk][wdst + 8]  = w2;
        *(float4*)&Ws[wk][wdst + 12] = w3;
        __syncthreads();

#pragma unroll
        for (int k = 0; k < 16; ++k) {
            const float4 a0 = *(const float4*)&Xs[k][ty * 8];
            const float4 a1 = *(const float4*)&Xs[k][ty * 8 + 4];
            const float4 b0 = *(const float4*)&Ws[k][tx * 4];
            const float4 b1 = *(const float4*)&Ws[k][128 + tx * 4];
            const float am[8] = {a0.x, a0.y, a0.z, a0.w, a1.x, a1.y, a1.z, a1.w};
            const float bn[8] = {b0.x, b0.y, b0.z, b0.w, b1.x, b1.y, b1.z, b1.w};
#pragma unroll
            for (int m = 0; m < 8; ++m)
#pragma unroll
                for (int n = 0; n < 8; ++n)
                    acc[m][n] = fmaf(am[m], bn[n], acc[m][n]);
        }
    }

    const int c0 = tx * 4;
#pragma unroll
    for (int m = 0; m < 8; ++m) {
        const int r = row0 + ty * 8 + m;
        if (r < N) {
            *(float4*)&S1[(size_t)r * D + c0] =
                make_float4(acc[m][0], acc[m][1], acc[m][2], acc[m][3]);
            *(float4*)&S2[(size_t)r * D + c0] =
                make_float4(acc[m][4], acc[m][5], acc[m][6], acc[m][7]);
        }
    }
}

// ---------------------------------------------------------------------------
// CSR construction: zero counts -> histogram -> 2-level exclusive scan -> scatter
// ---------------------------------------------------------------------------
__global__ void zero2(int* __restrict__ a, int* __restrict__ b, int n)
{
    int i = blockIdx.x * blockDim.x + threadIdx.x;
    if (i < n) { a[i] = 0; b[i] = 0; }
}

__global__ void hist2(const int* __restrict__ r0, const int* __restrict__ r1,
                      int* __restrict__ c0, int* __restrict__ c1, int E)
{
    int i = blockIdx.x * blockDim.x + threadIdx.x;
    if (i < E) {
        atomicAdd(&c0[r0[i]], 1);
        atomicAdd(&c1[r1[i]], 1);
    }
}

// per-block exclusive scan over 2048 elements; writes block sums
__global__ __launch_bounds__(256) void scan_blocks(const int* __restrict__ cnt,
                                                   int* __restrict__ excl,
                                                   int* __restrict__ bsum, int n)
{
    __shared__ int sh[256];
    const int tid = threadIdx.x;
    const int base = blockIdx.x * 2048 + tid * 8;
    int v[8];
    int t = 0;
#pragma unroll
    for (int j = 0; j < 8; ++j) {
        const int x = (base + j < n) ? cnt[base + j] : 0;
        v[j] = t;
        t += x;
    }
    sh[tid] = t;
    __syncthreads();
    int val = t;
    for (int off = 1; off < 256; off <<= 1) {
        const int y = (tid >= off) ? sh[tid - off] : 0;
        __syncthreads();
        val += y;
        sh[tid] = val;
        __syncthreads();
    }
    const int thr_excl = val - t;
#pragma unroll
    for (int j = 0; j < 8; ++j)
        if (base + j < n) excl[base + j] = thr_excl + v[j];
    if (tid == 255) bsum[blockIdx.x] = val;
}

// single-block exclusive scan of block sums (in place), nb <= 256.
// gridDim.x = 2: block 0 -> bsum0, block 1 -> bsum1.
__global__ __launch_bounds__(256) void scan_top2(int* __restrict__ bsum0,
                                                 int* __restrict__ bsum1, int nb)
{
    int* bsum = (blockIdx.x == 0) ? bsum0 : bsum1;
    __shared__ int sh[256];
    const int tid = threadIdx.x;
    const int x = (tid < nb) ? bsum[tid] : 0;
    sh[tid] = x;
    __syncthreads();
    int val = x;
    for (int off = 1; off < 256; off <<= 1) {
        const int y = (tid >= off) ? sh[tid - off] : 0;
        __syncthreads();
        val += y;
        sh[tid] = val;
        __syncthreads();
    }
    if (tid < nb) bsum[tid] = val - x;   // exclusive
}

// add block offsets; copy to cursor; write excl[n] = total
__global__ __launch_bounds__(256) void scan_add(int* __restrict__ excl,
                                                int* __restrict__ cur,
                                                const int* __restrict__ bsum,
                                                int n, int total)
{
    const int off = bsum[blockIdx.x];
    const int base = blockIdx.x * 2048 + threadIdx.x * 8;
#pragma unroll
    for (int j = 0; j < 8; ++j) {
        const int i = base + j;
        if (i < n) {
            const int v = excl[i] + off;
            excl[i] = v;
            cur[i] = v;
        }
    }
    if (blockIdx.x == 0 && threadIdx.x == 0) excl[n] = total;
}

// scatter into packed (col, val_bits) int2 records — one 8B store per edge
__global__ void scatter2(const int* __restrict__ r0, const int* __restrict__ c0s,
                         const float* __restrict__ v0s,
                         const int* __restrict__ r1, const int* __restrict__ c1s,
                         const float* __restrict__ v1s,
                         int* __restrict__ cur0, int* __restrict__ cur1,
                         int2* __restrict__ edgep0, int2* __restrict__ edgep1, int E)
{
    int i = blockIdx.x * blockDim.x + threadIdx.x;
    if (i < E) {
        int r = r0[i];
        int p = atomicAdd(&cur0[r], 1);
        edgep0[p] = make_int2(c0s[i], __float_as_int(v0s[i]));
        r = r1[i];
        p = atomicAdd(&cur1[r], 1);
        edgep1[p] = make_int2(c1s[i], __float_as_int(v1s[i]));
    }
}

// ---------------------------------------------------------------------------
// SpMM: one wave per output row. The two 32-lane halves process alternating
// edges (stride 2) of the row's list; each lane gathers float4 (16B) so a
// half-wave covers the full 128-col row. Edge metadata is a packed int2
// (col, val) -> one dwordx2 load per edge. Unroll depth 4 -> up to 8
// independent dwordx4 gathers in flight per wave. End: cross-half
// shuffle-add; half 0 adds bias and writes the row exactly once.
// ---------------------------------------------------------------------------
__global__ __launch_bounds__(256) void spmm_csr(
    const float* __restrict__ S1, const float* __restrict__ S2,
    const int* __restrict__ rs0, const int2* __restrict__ edgep0,
    const int* __restrict__ rs1, const int2* __restrict__ edgep1,
    const float* __restrict__ bias, float* __restrict__ out, int N)
{
    const int row = blockIdx.x * 4 + (threadIdx.x >> 6);
    if (row >= N) return;
    const int lane = threadIdx.x & 63;
    const int half = lane >> 5;       // 0: even edges, 1: odd edges
    const int c4 = (lane & 31) * 4;   // this lane's 4 columns

    float4 acc = make_float4(0.f, 0.f, 0.f, 0.f);

#pragma unroll
    for (int adj = 0; adj < 2; ++adj) {
        const float* __restrict__ S     = adj ? S2     : S1;
        const int*   __restrict__ rs    = adj ? rs1    : rs0;
        const int2*  __restrict__ edgep = adj ? edgep1 : edgep0;

        const int e = rs[row + 1];
        int i = rs[row] + half;
        // 4-deep: i, i+2, i+4, i+6 valid
        for (; i + 6 < e; i += 8) {
            const int2 e0 = edgep[i];
            const int2 e1 = edgep[i + 2];
            const int2 e2 = edgep[i + 4];
            const int2 e3 = edgep[i + 6];
            const float4 x0 = *(const float4*)&S[(size_t)e0.x * D + c4];
            const float4 x1 = *(const float4*)&S[(size_t)e1.x * D + c4];
            const float4 x2 = *(const float4*)&S[(size_t)e2.x * D + c4];
            const float4 x3 = *(const float4*)&S[(size_t)e3.x * D + c4];
            const float v0 = __int_as_float(e0.y), v1 = __int_as_float(e1.y);
            const float v2 = __int_as_float(e2.y), v3 = __int_as_float(e3.y);
            acc.x = fmaf(v0, x0.x, acc.x); acc.y = fmaf(v0, x0.y, acc.y);
            acc.z = fmaf(v0, x0.z, acc.z); acc.w = fmaf(v0, x0.w, acc.w);
            acc.x = fmaf(v1, x1.x, acc.x); acc.y = fmaf(v1, x1.y, acc.y);
            acc.z = fmaf(v1, x1.z, acc.z); acc.w = fmaf(v1, x1.w, acc.w);
            acc.x = fmaf(v2, x2.x, acc.x); acc.y = fmaf(v2, x2.y, acc.y);
            acc.z = fmaf(v2, x2.z, acc.z); acc.w = fmaf(v2, x2.w, acc.w);
            acc.x = fmaf(v3, x3.x, acc.x); acc.y = fmaf(v3, x3.y, acc.y);
            acc.z = fmaf(v3, x3.z, acc.z); acc.w = fmaf(v3, x3.w, acc.w);
        }
        // 2-deep: i, i+2 valid
        for (; i + 2 < e; i += 4) {
            const int2 e0 = edgep[i];
            const int2 e1 = edgep[i + 2];
            const float4 x0 = *(const float4*)&S[(size_t)e0.x * D + c4];
            const float4 x1 = *(const float4*)&S[(size_t)e1.x * D + c4];
            const float v0 = __int_as_float(e0.y), v1 = __int_as_float(e1.y);
            acc.x = fmaf(v0, x0.x, acc.x); acc.y = fmaf(v0, x0.y, acc.y);
            acc.z = fmaf(v0, x0.z, acc.z); acc.w = fmaf(v0, x0.w, acc.w);
            acc.x = fmaf(v1, x1.x, acc.x); acc.y = fmaf(v1, x1.y, acc.y);
            acc.z = fmaf(v1, x1.z, acc.z); acc.w = fmaf(v1, x1.w, acc.w);
        }
        // tail
        for (; i < e; i += 2) {
            const int2 e0 = edgep[i];
            const float v = __int_as_float(e0.y);
            const float4 x = *(const float4*)&S[(size_t)e0.x * D + c4];
            acc.x = fmaf(v, x.x, acc.x); acc.y = fmaf(v, x.y, acc.y);
            acc.z = fmaf(v, x.z, acc.z); acc.w = fmaf(v, x.w, acc.w);
        }
    }

    // combine the two halves (each holds a partial sum for the SAME 4 cols)
    acc.x += __shfl(acc.x, lane ^ 32);
    acc.y += __shfl(acc.y, lane ^ 32);
    acc.z += __shfl(acc.z, lane ^ 32);
    acc.w += __shfl(acc.w, lane ^ 32);

    if (half == 0) {
        const float4 b = *(const float4*)&bias[c4];
        acc.x += b.x; acc.y += b.y; acc.z += b.z; acc.w += b.w;
        *(float4*)&out[(size_t)row * D + c4] = acc;
    }
}

// ---------------------------------------------------------------------------
// Fallback (if ws too small for CSR arrays): init out with bias, atomic scatter.
// ---------------------------------------------------------------------------
__global__ void init_out(const float* __restrict__ bias, float* __restrict__ out, int total)
{
    int i = blockIdx.x * blockDim.x + threadIdx.x;
    if (i < total) out[i] = bias[i & (D - 1)];
}

__global__ __launch_bounds__(256) void spmm_atomic(const float* __restrict__ S,
    const int* __restrict__ rows, const int* __restrict__ cols,
    const float* __restrict__ vals, float* __restrict__ out, int E)
{
    const int e = blockIdx.x * 4 + (threadIdx.x >> 6);
    const int lane = threadIdx.x & 63;
    if (e >= E) return;
    const int r = rows[e], c = cols[e];
    const float v = vals[e];
    const float2 x = *(const float2*)&S[(size_t)c * D + lane * 2];
    atomicAdd(&out[(size_t)r * D + lane * 2 + 0], v * x.x);
    atomicAdd(&out[(size_t)r * D + lane * 2 + 1], v * x.y);
}

// ---------------------------------------------------------------------------
extern "C" void kernel_launch(void* const* d_in, const int* in_sizes, int n_in,
                              void* d_out, int out_size, void* d_ws, size_t ws_size,
                              hipStream_t stream)
{
    const float* X     = (const float*)d_in[0];
    const float* W1    = (const float*)d_in[1];
    const float* W2    = (const float*)d_in[2];
    const float* bias  = (const float*)d_in[3];
    const float* vals0 = (const float*)d_in[4];
    const float* vals1 = (const float*)d_in[5];
    const int*   rows0 = (const int*)d_in[6];
    const int*   cols0 = (const int*)d_in[7];
    const int*   rows1 = (const int*)d_in[8];
    const int*   cols1 = (const int*)d_in[9];
    float* out = (float*)d_out;

    const int N = in_sizes[0] / D;
    const int E = in_sizes[4];
    const int NB = (N + 2047) / 2048;   // scan blocks (<=256)

    auto aln = [](size_t x) { return (x + 255) & ~(size_t)255; };
    char* base = (char*)d_ws;
    size_t off = 0;
    float* S1 = (float*)(base + off); off += aln((size_t)N * D * sizeof(float));
    float* S2 = (float*)(base + off); off += aln((size_t)N * D * sizeof(float));
    int* rs0   = (int*)(base + off); off += aln((size_t)(N + 1) * 4);
    int* rs1   = (int*)(base + off); off += aln((size_t)(N + 1) * 4);
    int* cur0  = (int*)(base + off); off += aln((size_t)N * 4);
    int* cur1  = (int*)(base + off); off += aln((size_t)N * 4);
    int* cnt0  = (int*)(base + off); off += aln((size_t)N * 4);
    int* cnt1  = (int*)(base + off); off += aln((size_t)N * 4);
    int* bsum0 = (int*)(base + off); off += aln(256 * 4);
    int* bsum1 = (int*)(base + off); off += aln(256 * 4);
    int2* edgep0 = (int2*)(base + off); off += aln((size_t)E * 8);
    int2* edgep1 = (int2*)(base + off); off += aln((size_t)E * 8);
    const size_t need_full = off;

    // Phase 1: dense supports
    gemm_dual<<<(N + 63) / 64, 256, 0, stream>>>(X, W1, W2, S1, S2, N);

    if (ws_size >= need_full) {
        // Phase 2: CSR build
        zero2<<<(N + 255) / 256, 256, 0, stream>>>(cnt0, cnt1, N);
        hist2<<<(E + 255) / 256, 256, 0, stream>>>(rows0, rows1, cnt0, cnt1, E);
        scan_blocks<<<NB, 256, 0, stream>>>(cnt0, rs0, bsum0, N);
        scan_blocks<<<NB, 256, 0, stream>>>(cnt1, rs1, bsum1, N);
        scan_top2<<<2, 256, 0, stream>>>(bsum0, bsum1, NB);
        scan_add<<<NB, 256, 0, stream>>>(rs0, cur0, bsum0, N, E);
        scan_add<<<NB, 256, 0, stream>>>(rs1, cur1, bsum1, N, E);
        scatter2<<<(E + 255) / 256, 256, 0, stream>>>(rows0, cols0, vals0,
                                                      rows1, cols1, vals1,
                                                      cur0, cur1,
                                                      edgep0, edgep1, E);
        // Phase 3: gather SpMM, one write per out row
        spmm_csr<<<(N + 3) / 4, 256, 0, stream>>>(S1, S2, rs0, edgep0,
                                                  rs1, edgep1, bias, out, N);
    } else {
        // Fallback: atomic scatter
        init_out<<<(N * D + 255) / 256, 256, 0, stream>>>(bias, out, N * D);
        spmm_atomic<<<(E + 3) / 4, 256, 0, stream>>>(S1, rows0, cols0, vals0, out, E);
        spmm_atomic<<<(E + 3) / 4, 256, 0, stream>>>(S2, rows1, cols1, vals1, out, E);
    }
}

// Round 5
// 626.811 us; speedup vs baseline: 1.2765x; 1.2765x over previous
//
#include <hip/hip_runtime.h>

#define D 128
#define RPB 256          // rows per bucket (pow2: bucket = row >> 8, lrow = row & 255)
#define NBK_MAX 512      // scan width in bin_edges; supports N <= 131072
#define C_EPT 8          // edges per thread in bin_edges (WG=512 -> 4096/chunk)
#define C_CHUNK 4096
#define DCAP 6144        // bucket_to_csr LDS stage capacity (mean 4096, sd 64)

// ---------------------------------------------------------------------------
// Fused dual GEMM: S1 = X @ W1, S2 = X @ W2.  X:[N,128] f32, W:[128,128].
// 64x256 tile, per-thread 8x8. No fp32 MFMA on CDNA4 -> vector ALU.
// ---------------------------------------------------------------------------
__global__ __launch_bounds__(256) void gemm_dual(const float* __restrict__ X,
                                                 const float* __restrict__ W1,
                                                 const float* __restrict__ W2,
                                                 float* __restrict__ S1,
                                                 float* __restrict__ S2, int N)
{
    __shared__ float Xs[16][64];    // transposed: Xs[k][m]
    __shared__ float Ws[16][256];   // Ws[k][n]  (n<128 -> W1, n>=128 -> W2)

    const int tid = threadIdx.x;
    const int tx = tid & 31;   // col group 0..31 (4 cols per matrix)
    const int ty = tid >> 5;   // row group 0..7  (8 rows)
    const int row0 = blockIdx.x * 64;

    float acc[8][8];
#pragma unroll
    for (int m = 0; m < 8; ++m)
#pragma unroll
        for (int n = 0; n < 8; ++n) acc[m][n] = 0.f;

    const int xr = tid >> 2;          // 0..63 (row within tile)
    const int xk = (tid & 3) << 2;    // 0,4,8,12 (k offset)
    const int wk = tid >> 4;          // 0..15 (k within tile)
    const int seg = tid & 15;         // 0..15 (16-col segment)
    const float* wsrc = (seg < 8) ? W1 : W2;
    const int wc = (seg & 7) << 4;    // 0..112 source col
    const int wdst = ((seg < 8) ? 0 : 128) + wc;

    for (int k0 = 0; k0 < 128; k0 += 16) {
        float4 xv = make_float4(0.f, 0.f, 0.f, 0.f);
        const int grow = row0 + xr;
        if (grow < N) xv = *(const float4*)&X[(size_t)grow * D + k0 + xk];
        const float* wsp = &wsrc[(size_t)(k0 + wk) * D + wc];
        const float4 w0 = *(const float4*)(wsp + 0);
        const float4 w1 = *(const float4*)(wsp + 4);
        const float4 w2 = *(const float4*)(wsp + 8);
        const float4 w3 = *(const float4*)(wsp + 12);

        __syncthreads();
        Xs[xk + 0][xr] = xv.x;
        Xs[xk + 1][xr] = xv.y;
        Xs[xk + 2][xr] = xv.z;
        Xs[xk + 3][xr] = xv.w;
        *(float4*)&Ws[wk][wdst + 0]  = w0;
        *(float4*)&Ws[wk][wdst + 4]  = w1;
        *(float4*)&Ws[wk][wdst + 8]  = w2;
        *(float4*)&Ws[wk][wdst + 12] = w3;
        __syncthreads();

#pragma unroll
        for (int k = 0; k < 16; ++k) {
            const float4 a0 = *(const float4*)&Xs[k][ty * 8];
            const float4 a1 = *(const float4*)&Xs[k][ty * 8 + 4];
            const float4 b0 = *(const float4*)&Ws[k][tx * 4];
            const float4 b1 = *(const float4*)&Ws[k][128 + tx * 4];
            const float am[8] = {a0.x, a0.y, a0.z, a0.w, a1.x, a1.y, a1.z, a1.w};
            const float bn[8] = {b0.x, b0.y, b0.z, b0.w, b1.x, b1.y, b1.z, b1.w};
#pragma unroll
            for (int m = 0; m < 8; ++m)
#pragma unroll
                for (int n = 0; n < 8; ++n)
                    acc[m][n] = fmaf(am[m], bn[n], acc[m][n]);
        }
    }

    const int c0 = tx * 4;
#pragma unroll
    for (int m = 0; m < 8; ++m) {
        const int r = row0 + ty * 8 + m;
        if (r < N) {
            *(float4*)&S1[(size_t)r * D + c0] =
                make_float4(acc[m][0], acc[m][1], acc[m][2], acc[m][3]);
            *(float4*)&S2[(size_t)r * D + c0] =
                make_float4(acc[m][4], acc[m][5], acc[m][6], acc[m][7]);
        }
    }
}

// ---------------------------------------------------------------------------
// CSR construction
// ---------------------------------------------------------------------------
__global__ void zero2(int* __restrict__ a, int* __restrict__ b, int n)
{
    int i = blockIdx.x * blockDim.x + threadIdx.x;
    if (i < n) { a[i] = 0; b[i] = 0; }
}

__global__ void hist2(const int* __restrict__ r0, const int* __restrict__ r1,
                      int* __restrict__ c0, int* __restrict__ c1, int E)
{
    int i = blockIdx.x * blockDim.x + threadIdx.x;
    if (i < E) {
        atomicAdd(&c0[r0[i]], 1);
        atomicAdd(&c1[r1[i]], 1);
    }
}

// per-block exclusive scan over 2048 elements; writes block sums
__global__ __launch_bounds__(256) void scan_blocks(const int* __restrict__ cnt,
                                                   int* __restrict__ excl,
                                                   int* __restrict__ bsum, int n)
{
    __shared__ int sh[256];
    const int tid = threadIdx.x;
    const int base = blockIdx.x * 2048 + tid * 8;
    int v[8];
    int t = 0;
#pragma unroll
    for (int j = 0; j < 8; ++j) {
        const int x = (base + j < n) ? cnt[base + j] : 0;
        v[j] = t;
        t += x;
    }
    sh[tid] = t;
    __syncthreads();
    int val = t;
    for (int off = 1; off < 256; off <<= 1) {
        const int y = (tid >= off) ? sh[tid - off] : 0;
        __syncthreads();
        val += y;
        sh[tid] = val;
        __syncthreads();
    }
    const int thr_excl = val - t;
#pragma unroll
    for (int j = 0; j < 8; ++j)
        if (base + j < n) excl[base + j] = thr_excl + v[j];
    if (tid == 255) bsum[blockIdx.x] = val;
}

// single-block exclusive scan of block sums (in place), nb <= 256; grid=2
__global__ __launch_bounds__(256) void scan_top2(int* __restrict__ bsum0,
                                                 int* __restrict__ bsum1, int nb)
{
    int* bsum = (blockIdx.x == 0) ? bsum0 : bsum1;
    __shared__ int sh[256];
    const int tid = threadIdx.x;
    const int x = (tid < nb) ? bsum[tid] : 0;
    sh[tid] = x;
    __syncthreads();
    int val = x;
    for (int off = 1; off < 256; off <<= 1) {
        const int y = (tid >= off) ? sh[tid - off] : 0;
        __syncthreads();
        val += y;
        sh[tid] = val;
        __syncthreads();
    }
    if (tid < nb) bsum[tid] = val - x;   // exclusive
}

// add block offsets; copy to cursor; write excl[n] = total
__global__ __launch_bounds__(256) void scan_add(int* __restrict__ excl,
                                                int* __restrict__ cur,
                                                const int* __restrict__ bsum,
                                                int n, int total)
{
    const int off = bsum[blockIdx.x];
    const int base = blockIdx.x * 2048 + threadIdx.x * 8;
#pragma unroll
    for (int j = 0; j < 8; ++j) {
        const int i = base + j;
        if (i < n) {
            const int v = excl[i] + off;
            excl[i] = v;
            cur[i] = v;
        }
    }
    if (blockIdx.x == 0 && threadIdx.x == 0) excl[n] = total;
}

// bkcur[b] = rs[b*RPB] : bucket write cursors start at bucket CSR base
__global__ void init_bkcur(const int* __restrict__ rs0, const int* __restrict__ rs1,
                           int* __restrict__ bkcur0, int* __restrict__ bkcur1, int nbk)
{
    int i = blockIdx.x * blockDim.x + threadIdx.x;
    if (i < nbk) {
        bkcur0[i] = rs0[i << 8];
        bkcur1[i] = rs1[i << 8];
    }
}

// ---------------------------------------------------------------------------
// bin_edges: LDS-staged scatter into row-buckets (bucket = row>>8).
// WG=512 handles 4096 edges: LDS bucket hist -> scan -> one global atomicAdd
// per (WG,bucket) range reservation -> LDS reorder -> run-coalesced flush.
// Record: meta = (lrow<<24)|col (col < 2^24), val bits.
// ---------------------------------------------------------------------------
__global__ __launch_bounds__(512) void bin_edges(
    const int* __restrict__ rows0, const int* __restrict__ cols0, const float* __restrict__ vals0,
    const int* __restrict__ rows1, const int* __restrict__ cols1, const float* __restrict__ vals1,
    int* __restrict__ bkcur0, int* __restrict__ bkcur1,
    int2* __restrict__ binned0, int2* __restrict__ binned1,
    int E, int nchunk)
{
    const bool a1 = (int)blockIdx.x >= nchunk;
    const int chunk = a1 ? (int)blockIdx.x - nchunk : (int)blockIdx.x;
    const int*   __restrict__ rows  = a1 ? rows1  : rows0;
    const int*   __restrict__ cols  = a1 ? cols1  : cols0;
    const float* __restrict__ vals  = a1 ? vals1  : vals0;
    int*         __restrict__ bkcur = a1 ? bkcur1 : bkcur0;
    int2*        __restrict__ binned= a1 ? binned1: binned0;

    __shared__ int lcnt[NBK_MAX];
    __shared__ int lstart[NBK_MAX + 1];
    __shared__ int lbase[NBK_MAX];
    __shared__ int lofs[NBK_MAX];
    __shared__ int smeta[C_CHUNK];
    __shared__ int sval[C_CHUNK];

    const int tid = threadIdx.x;
    const int e0 = chunk * C_CHUNK;
    const int m = min(C_CHUNK, E - e0);

    lcnt[tid] = 0;
    __syncthreads();

    int rr[C_EPT];
#pragma unroll
    for (int k = 0; k < C_EPT; ++k) {
        const int j = tid + k * 512;
        rr[k] = (j < m) ? rows[e0 + j] : -1;
        if (rr[k] >= 0) atomicAdd(&lcnt[rr[k] >> 8], 1);
    }
    __syncthreads();

    // exclusive scan over 512 buckets (Hillis-Steele)
    const int own = lcnt[tid];
    lstart[tid] = own;
    __syncthreads();
    int val = own;
    for (int off = 1; off < 512; off <<= 1) {
        const int y = (tid >= off) ? lstart[tid - off] : 0;
        __syncthreads();
        val += y;
        lstart[tid] = val;
        __syncthreads();
    }
    const int excl = val - own;
    lstart[tid] = excl;
    if (tid == 511) lstart[512] = val;   // = m
    if (own > 0) lbase[tid] = atomicAdd(&bkcur[tid], own);
    lofs[tid] = excl;
    __syncthreads();

    // stage records into LDS in bucket-sorted order
#pragma unroll
    for (int k = 0; k < C_EPT; ++k) {
        const int j = tid + k * 512;
        if (j < m) {
            const int r = rr[k];
            const int slot = atomicAdd(&lofs[r >> 8], 1);
            smeta[slot] = ((r & 255) << 24) | cols[e0 + j];
            sval[slot]  = __float_as_int(vals[e0 + j]);
        }
    }
    __syncthreads();

    // flush: consecutive threads write consecutive addresses within bucket runs
#pragma unroll
    for (int k = 0; k < C_EPT; ++k) {
        const int j = tid + k * 512;
        if (j < m) {
            int lo = 0;
#pragma unroll
            for (int st = 256; st > 0; st >>= 1)
                if (lstart[lo + st] <= j) lo += st;
            binned[lbase[lo] + (j - lstart[lo])] = make_int2(smeta[j], sval[j]);
        }
    }
}

// ---------------------------------------------------------------------------
// bucket_to_csr: WG per bucket. Loads the bucket's records, local 256-row
// histogram + scan, LDS reorder to exact CSR order, fully sequential flush.
// ---------------------------------------------------------------------------
__global__ __launch_bounds__(256) void bucket_to_csr(
    const int2* __restrict__ binned0, const int2* __restrict__ binned1,
    const int* __restrict__ rs0, const int* __restrict__ rs1,
    int* __restrict__ cur0, int* __restrict__ cur1,
    int2* __restrict__ edgep0, int2* __restrict__ edgep1,
    int N, int nbk)
{
    const bool a1 = (int)blockIdx.x >= nbk;
    const int b = a1 ? (int)blockIdx.x - nbk : (int)blockIdx.x;
    const int2* __restrict__ binned = a1 ? binned1 : binned0;
    const int*  __restrict__ rs     = a1 ? rs1     : rs0;
    int2*       __restrict__ edgep  = a1 ? edgep1  : edgep0;

    const int r0 = b << 8;
    const int r1 = min(r0 + 256, N);
    const int segbase = rs[r0];
    const int cnt = rs[r1] - segbase;

    __shared__ int lhist[256];
    __shared__ int lstartD[256];
    __shared__ int smeta[DCAP];
    __shared__ int sval[DCAP];

    const int tid = threadIdx.x;
    lhist[tid] = 0;
    __syncthreads();

    if (cnt <= DCAP) {
        for (int j = tid; j < cnt; j += 256) {
            const int2 rec = binned[segbase + j];
            atomicAdd(&lhist[((unsigned)rec.x) >> 24], 1);
        }
        __syncthreads();
        const int own = lhist[tid];
        lstartD[tid] = own;
        __syncthreads();
        int val = own;
        for (int off = 1; off < 256; off <<= 1) {
            const int y = (tid >= off) ? lstartD[tid - off] : 0;
            __syncthreads();
            val += y;
            lstartD[tid] = val;
            __syncthreads();
        }
        lstartD[tid] = val - own;   // exclusive; reused as per-row cursors
        __syncthreads();
        for (int j = tid; j < cnt; j += 256) {
            const int2 rec = binned[segbase + j];
            const int lrow = ((unsigned)rec.x) >> 24;
            const int slot = atomicAdd(&lstartD[lrow], 1);
            smeta[slot] = rec.x & 0xFFFFFF;
            sval[slot]  = rec.y;
        }
        __syncthreads();
        for (int j = tid; j < cnt; j += 256)
            edgep[segbase + j] = make_int2(smeta[j], sval[j]);
    } else {
        // statistically unreachable for this data; correct direct scatter
        int* __restrict__ cur = a1 ? cur1 : cur0;
        for (int j = tid; j < cnt; j += 256) {
            const int2 rec = binned[segbase + j];
            const int row = r0 + (int)(((unsigned)rec.x) >> 24);
            const int p = atomicAdd(&cur[row], 1);
            edgep[p] = make_int2(rec.x & 0xFFFFFF, rec.y);
        }
    }
}

// ---------------------------------------------------------------------------
// SpMM: one wave per output row; two 32-lane halves take alternating edges;
// each lane gathers float4 (16B). 4-deep unroll -> 8 gathers in flight/wave.
// ---------------------------------------------------------------------------
__global__ __launch_bounds__(256) void spmm_csr(
    const float* __restrict__ S1, const float* __restrict__ S2,
    const int* __restrict__ rs0, const int2* __restrict__ edgep0,
    const int* __restrict__ rs1, const int2* __restrict__ edgep1,
    const float* __restrict__ bias, float* __restrict__ out, int N)
{
    const int row = blockIdx.x * 4 + (threadIdx.x >> 6);
    if (row >= N) return;
    const int lane = threadIdx.x & 63;
    const int half = lane >> 5;       // 0: even edges, 1: odd edges
    const int c4 = (lane & 31) * 4;   // this lane's 4 columns

    float4 acc = make_float4(0.f, 0.f, 0.f, 0.f);

#pragma unroll
    for (int adj = 0; adj < 2; ++adj) {
        const float* __restrict__ S     = adj ? S2     : S1;
        const int*   __restrict__ rs    = adj ? rs1    : rs0;
        const int2*  __restrict__ edgep = adj ? edgep1 : edgep0;

        const int e = rs[row + 1];
        int i = rs[row] + half;
        for (; i + 6 < e; i += 8) {
            const int2 e0 = edgep[i];
            const int2 e1 = edgep[i + 2];
            const int2 e2 = edgep[i + 4];
            const int2 e3 = edgep[i + 6];
            const float4 x0 = *(const float4*)&S[(size_t)e0.x * D + c4];
            const float4 x1 = *(const float4*)&S[(size_t)e1.x * D + c4];
            const float4 x2 = *(const float4*)&S[(size_t)e2.x * D + c4];
            const float4 x3 = *(const float4*)&S[(size_t)e3.x * D + c4];
            const float v0 = __int_as_float(e0.y), v1 = __int_as_float(e1.y);
            const float v2 = __int_as_float(e2.y), v3 = __int_as_float(e3.y);
            acc.x = fmaf(v0, x0.x, acc.x); acc.y = fmaf(v0, x0.y, acc.y);
            acc.z = fmaf(v0, x0.z, acc.z); acc.w = fmaf(v0, x0.w, acc.w);
            acc.x = fmaf(v1, x1.x, acc.x); acc.y = fmaf(v1, x1.y, acc.y);
            acc.z = fmaf(v1, x1.z, acc.z); acc.w = fmaf(v1, x1.w, acc.w);
            acc.x = fmaf(v2, x2.x, acc.x); acc.y = fmaf(v2, x2.y, acc.y);
            acc.z = fmaf(v2, x2.z, acc.z); acc.w = fmaf(v2, x2.w, acc.w);
            acc.x = fmaf(v3, x3.x, acc.x); acc.y = fmaf(v3, x3.y, acc.y);
            acc.z = fmaf(v3, x3.z, acc.z); acc.w = fmaf(v3, x3.w, acc.w);
        }
        for (; i + 2 < e; i += 4) {
            const int2 e0 = edgep[i];
            const int2 e1 = edgep[i + 2];
            const float4 x0 = *(const float4*)&S[(size_t)e0.x * D + c4];
            const float4 x1 = *(const float4*)&S[(size_t)e1.x * D + c4];
            const float v0 = __int_as_float(e0.y), v1 = __int_as_float(e1.y);
            acc.x = fmaf(v0, x0.x, acc.x); acc.y = fmaf(v0, x0.y, acc.y);
            acc.z = fmaf(v0, x0.z, acc.z); acc.w = fmaf(v0, x0.w, acc.w);
            acc.x = fmaf(v1, x1.x, acc.x); acc.y = fmaf(v1, x1.y, acc.y);
            acc.z = fmaf(v1, x1.z, acc.z); acc.w = fmaf(v1, x1.w, acc.w);
        }
        for (; i < e; i += 2) {
            const int2 e0 = edgep[i];
            const float v = __int_as_float(e0.y);
            const float4 x = *(const float4*)&S[(size_t)e0.x * D + c4];
            acc.x = fmaf(v, x.x, acc.x); acc.y = fmaf(v, x.y, acc.y);
            acc.z = fmaf(v, x.z, acc.z); acc.w = fmaf(v, x.w, acc.w);
        }
    }

    acc.x += __shfl(acc.x, lane ^ 32);
    acc.y += __shfl(acc.y, lane ^ 32);
    acc.z += __shfl(acc.z, lane ^ 32);
    acc.w += __shfl(acc.w, lane ^ 32);

    if (half == 0) {
        const float4 b = *(const float4*)&bias[c4];
        acc.x += b.x; acc.y += b.y; acc.z += b.z; acc.w += b.w;
        *(float4*)&out[(size_t)row * D + c4] = acc;
    }
}

// ---------------------------------------------------------------------------
// Fallback (ws too small): init out with bias, atomic scatter.
// ---------------------------------------------------------------------------
__global__ void init_out(const float* __restrict__ bias, float* __restrict__ out, int total)
{
    int i = blockIdx.x * blockDim.x + threadIdx.x;
    if (i < total) out[i] = bias[i & (D - 1)];
}

__global__ __launch_bounds__(256) void spmm_atomic(const float* __restrict__ S,
    const int* __restrict__ rows, const int* __restrict__ cols,
    const float* __restrict__ vals, float* __restrict__ out, int E)
{
    const int e = blockIdx.x * 4 + (threadIdx.x >> 6);
    const int lane = threadIdx.x & 63;
    if (e >= E) return;
    const int r = rows[e], c = cols[e];
    const float v = vals[e];
    const float2 x = *(const float2*)&S[(size_t)c * D + lane * 2];
    atomicAdd(&out[(size_t)r * D + lane * 2 + 0], v * x.x);
    atomicAdd(&out[(size_t)r * D + lane * 2 + 1], v * x.y);
}

// ---------------------------------------------------------------------------
extern "C" void kernel_launch(void* const* d_in, const int* in_sizes, int n_in,
                              void* d_out, int out_size, void* d_ws, size_t ws_size,
                              hipStream_t stream)
{
    const float* X     = (const float*)d_in[0];
    const float* W1    = (const float*)d_in[1];
    const float* W2    = (const float*)d_in[2];
    const float* bias  = (const float*)d_in[3];
    const float* vals0 = (const float*)d_in[4];
    const float* vals1 = (const float*)d_in[5];
    const int*   rows0 = (const int*)d_in[6];
    const int*   cols0 = (const int*)d_in[7];
    const int*   rows1 = (const int*)d_in[8];
    const int*   cols1 = (const int*)d_in[9];
    float* out = (float*)d_out;

    const int N = in_sizes[0] / D;
    const int E = in_sizes[4];
    const int NB = (N + 2047) / 2048;        // row-scan blocks (<=256)
    const int nbk = (N + RPB - 1) / RPB;     // row buckets
    const int nchunk = (E + C_CHUNK - 1) / C_CHUNK;

    auto aln = [](size_t x) { return (x + 255) & ~(size_t)255; };
    char* base = (char*)d_ws;
    size_t off = 0;
    float* S1 = (float*)(base + off); off += aln((size_t)N * D * sizeof(float));
    float* S2 = (float*)(base + off); off += aln((size_t)N * D * sizeof(float));
    // binned arrays alias S1/S2 region (dead before gemm_dual runs)
    int2* binned0 = (int2*)S1;
    int2* binned1 = (int2*)S2;
    int* rs0   = (int*)(base + off); off += aln((size_t)(N + 1) * 4);
    int* rs1   = (int*)(base + off); off += aln((size_t)(N + 1) * 4);
    int* cur0  = (int*)(base + off); off += aln((size_t)N * 4);
    int* cur1  = (int*)(base + off); off += aln((size_t)N * 4);
    int* cnt0  = (int*)(base + off); off += aln((size_t)N * 4);
    int* cnt1  = (int*)(base + off); off += aln((size_t)N * 4);
    int* bsum0 = (int*)(base + off); off += aln(256 * 4);
    int* bsum1 = (int*)(base + off); off += aln(256 * 4);
    int* bkcur0 = (int*)(base + off); off += aln((size_t)nbk * 4);
    int* bkcur1 = (int*)(base + off); off += aln((size_t)nbk * 4);
    int2* edgep0 = (int2*)(base + off); off += aln((size_t)E * 8);
    int2* edgep1 = (int2*)(base + off); off += aln((size_t)E * 8);
    const size_t need_full = off;

    const bool ok = (ws_size >= need_full) && (nbk <= NBK_MAX) &&
                    ((size_t)E * 8 <= (size_t)N * D * sizeof(float));

    if (ok) {
        // Phase A: CSR build (before gemm — binned aliases S1/S2)
        zero2<<<(N + 255) / 256, 256, 0, stream>>>(cnt0, cnt1, N);
        hist2<<<(E + 255) / 256, 256, 0, stream>>>(rows0, rows1, cnt0, cnt1, E);
        scan_blocks<<<NB, 256, 0, stream>>>(cnt0, rs0, bsum0, N);
        scan_blocks<<<NB, 256, 0, stream>>>(cnt1, rs1, bsum1, N);
        scan_top2<<<2, 256, 0, stream>>>(bsum0, bsum1, NB);
        scan_add<<<NB, 256, 0, stream>>>(rs0, cur0, bsum0, N, E);
        scan_add<<<NB, 256, 0, stream>>>(rs1, cur1, bsum1, N, E);
        init_bkcur<<<(nbk + 255) / 256, 256, 0, stream>>>(rs0, rs1, bkcur0, bkcur1, nbk);
        bin_edges<<<2 * nchunk, 512, 0, stream>>>(rows0, cols0, vals0,
                                                  rows1, cols1, vals1,
                                                  bkcur0, bkcur1, binned0, binned1,
                                                  E, nchunk);
        bucket_to_csr<<<2 * nbk, 256, 0, stream>>>(binned0, binned1, rs0, rs1,
                                                   cur0, cur1, edgep0, edgep1, N, nbk);
        // Phase B: dense supports (overwrites binned alias region)
        gemm_dual<<<(N + 63) / 64, 256, 0, stream>>>(X, W1, W2, S1, S2, N);
        // Phase C: gather SpMM, one write per out row
        spmm_csr<<<(N + 3) / 4, 256, 0, stream>>>(S1, S2, rs0, edgep0,
                                                  rs1, edgep1, bias, out, N);
    } else {
        // Fallback: atomic scatter
        gemm_dual<<<(N + 63) / 64, 256, 0, stream>>>(X, W1, W2, S1, S2, N);
        init_out<<<(N * D + 255) / 256, 256, 0, stream>>>(bias, out, N * D);
        spmm_atomic<<<(E + 3) / 4, 256, 0, stream>>>(S1, rows0, cols0, vals0, out, E);
        spmm_atomic<<<(E + 3) / 4, 256, 0, stream>>>(S2, rows1, cols1, vals1, out, E);
    }
}

// Round 7
// 487.858 us; speedup vs baseline: 1.6401x; 1.2848x over previous
//
#include <hip/hip_runtime.h>

#define D 128
#define RPB 256          // rows per bucket (bucket = row >> 8, lrow = row & 255)
#define NBK_MAX 512      // bucket-scan width; supports N <= 131072
#define C_EPT 8          // edges per thread in bin kernels (WG=512 -> 4096/chunk)
#define C_CHUNK 4096
#define DCAP 6144        // bucket_to_csr LDS capacity (mean 4096, sd ~64)

// ---------------------------------------------------------------------------
// Fused dual GEMM: S1 = X @ W1, S2 = X @ W2.  X:[N,128] f32, W:[128,128].
// 64x256 tile, per-thread 8x8. No fp32 MFMA on CDNA4 -> vector ALU.
// ---------------------------------------------------------------------------
__global__ __launch_bounds__(256) void gemm_dual(const float* __restrict__ X,
                                                 const float* __restrict__ W1,
                                                 const float* __restrict__ W2,
                                                 float* __restrict__ S1,
                                                 float* __restrict__ S2, int N)
{
    __shared__ float Xs[16][64];    // transposed: Xs[k][m]
    __shared__ float Ws[16][256];   // Ws[k][n]  (n<128 -> W1, n>=128 -> W2)

    const int tid = threadIdx.x;
    const int tx = tid & 31;   // col group 0..31 (4 cols per matrix)
    const int ty = tid >> 5;   // row group 0..7  (8 rows)
    const int row0 = blockIdx.x * 64;

    float acc[8][8];
#pragma unroll
    for (int m = 0; m < 8; ++m)
#pragma unroll
        for (int n = 0; n < 8; ++n) acc[m][n] = 0.f;

    const int xr = tid >> 2;          // 0..63 (row within tile)
    const int xk = (tid & 3) << 2;    // 0,4,8,12 (k offset)
    const int wk = tid >> 4;          // 0..15 (k within tile)
    const int seg = tid & 15;         // 0..15 (16-col segment)
    const float* wsrc = (seg < 8) ? W1 : W2;
    const int wc = (seg & 7) << 4;    // 0..112 source col
    const int wdst = ((seg < 8) ? 0 : 128) + wc;

    for (int k0 = 0; k0 < 128; k0 += 16) {
        float4 xv = make_float4(0.f, 0.f, 0.f, 0.f);
        const int grow = row0 + xr;
        if (grow < N) xv = *(const float4*)&X[(size_t)grow * D + k0 + xk];
        const float* wsp = &wsrc[(size_t)(k0 + wk) * D + wc];
        const float4 w0 = *(const float4*)(wsp + 0);
        const float4 w1 = *(const float4*)(wsp + 4);
        const float4 w2 = *(const float4*)(wsp + 8);
        const float4 w3 = *(const float4*)(wsp + 12);

        __syncthreads();
        Xs[xk + 0][xr] = xv.x;
        Xs[xk + 1][xr] = xv.y;
        Xs[xk + 2][xr] = xv.z;
        Xs[xk + 3][xr] = xv.w;
        *(float4*)&Ws[wk][wdst + 0]  = w0;
        *(float4*)&Ws[wk][wdst + 4]  = w1;
        *(float4*)&Ws[wk][wdst + 8]  = w2;
        *(float4*)&Ws[wk][wdst + 12] = w3;
        __syncthreads();

#pragma unroll
        for (int k = 0; k < 16; ++k) {
            const float4 a0 = *(const float4*)&Xs[k][ty * 8];
            const float4 a1 = *(const float4*)&Xs[k][ty * 8 + 4];
            const float4 b0 = *(const float4*)&Ws[k][tx * 4];
            const float4 b1 = *(const float4*)&Ws[k][128 + tx * 4];
            const float am[8] = {a0.x, a0.y, a0.z, a0.w, a1.x, a1.y, a1.z, a1.w};
            const float bn[8] = {b0.x, b0.y, b0.z, b0.w, b1.x, b1.y, b1.z, b1.w};
#pragma unroll
            for (int m = 0; m < 8; ++m)
#pragma unroll
                for (int n = 0; n < 8; ++n)
                    acc[m][n] = fmaf(am[m], bn[n], acc[m][n]);
        }
    }

    const int c0 = tx * 4;
#pragma unroll
    for (int m = 0; m < 8; ++m) {
        const int r = row0 + ty * 8 + m;
        if (r < N) {
            *(float4*)&S1[(size_t)r * D + c0] =
                make_float4(acc[m][0], acc[m][1], acc[m][2], acc[m][3]);
            *(float4*)&S2[(size_t)r * D + c0] =
                make_float4(acc[m][4], acc[m][5], acc[m][6], acc[m][7]);
        }
    }
}

// ---------------------------------------------------------------------------
// Bucket pipeline: zero_bcnt -> bin_count -> bucket_scan -> bin_edges
//                  -> bucket_to_csr (which also emits rs[])
// ---------------------------------------------------------------------------
__global__ void zero_bcnt(int* __restrict__ b0, int* __restrict__ b1, int nbk)
{
    int i = blockIdx.x * blockDim.x + threadIdx.x;
    if (i < nbk) { b0[i] = 0; b1[i] = 0; }
}

// per-WG LDS bucket histogram over a 4096-edge chunk, flush to global bcnt
__global__ __launch_bounds__(512) void bin_count(
    const int* __restrict__ rows0, const int* __restrict__ rows1,
    int* __restrict__ bcnt0, int* __restrict__ bcnt1, int E, int nchunk)
{
    const bool a1 = (int)blockIdx.x >= nchunk;
    const int chunk = a1 ? (int)blockIdx.x - nchunk : (int)blockIdx.x;
    const int* __restrict__ rows = a1 ? rows1 : rows0;
    int* __restrict__ bcnt = a1 ? bcnt1 : bcnt0;

    __shared__ int lcnt[NBK_MAX];
    const int tid = threadIdx.x;
    lcnt[tid] = 0;
    __syncthreads();
    const int e0 = chunk * C_CHUNK;
    const int m = min(C_CHUNK, E - e0);
#pragma unroll
    for (int k = 0; k < C_EPT; ++k) {
        const int j = tid + k * 512;
        if (j < m) atomicAdd(&lcnt[rows[e0 + j] >> 8], 1);
    }
    __syncthreads();
    if (lcnt[tid] > 0) atomicAdd(&bcnt[tid], lcnt[tid]);
}

// exclusive scan over nbk bucket counts (nbk <= 512); grid=2 (one per adj).
// writes bbase[0..nbk] (bbase[nbk]=E) and bkcur = bbase.
__global__ __launch_bounds__(512) void bucket_scan(
    const int* __restrict__ bcnt0, const int* __restrict__ bcnt1,
    int* __restrict__ bbase0, int* __restrict__ bbase1,
    int* __restrict__ bkcur0, int* __restrict__ bkcur1, int nbk, int E)
{
    const bool a1 = blockIdx.x == 1;
    const int* __restrict__ bcnt = a1 ? bcnt1 : bcnt0;
    int* __restrict__ bbase = a1 ? bbase1 : bbase0;
    int* __restrict__ bkcur = a1 ? bkcur1 : bkcur0;

    __shared__ int sh[512];
    const int tid = threadIdx.x;
    const int x = (tid < nbk) ? bcnt[tid] : 0;
    sh[tid] = x;
    __syncthreads();
    int val = x;
    for (int off = 1; off < 512; off <<= 1) {
        const int y = (tid >= off) ? sh[tid - off] : 0;
        __syncthreads();
        val += y;
        sh[tid] = val;
        __syncthreads();
    }
    if (tid < nbk) { bbase[tid] = val - x; bkcur[tid] = val - x; }
    if (tid == 0) bbase[nbk] = E;
}

// ---------------------------------------------------------------------------
// bin_edges: LDS-staged scatter into row-buckets (bucket = row>>8).
// WG=512 handles 4096 edges: LDS bucket hist -> scan -> one global atomicAdd
// per (WG,bucket) range reservation -> LDS reorder (bucket id memoized in
// sbucket) -> run-coalesced flush with direct LDS lookup (no binary search).
// Record: meta = (lrow<<24)|col (col < 2^24), val bits.
// ---------------------------------------------------------------------------
__global__ __launch_bounds__(512) void bin_edges(
    const int* __restrict__ rows0, const int* __restrict__ cols0, const float* __restrict__ vals0,
    const int* __restrict__ rows1, const int* __restrict__ cols1, const float* __restrict__ vals1,
    int* __restrict__ bkcur0, int* __restrict__ bkcur1,
    int2* __restrict__ binned0, int2* __restrict__ binned1,
    int E, int nchunk)
{
    const bool a1 = (int)blockIdx.x >= nchunk;
    const int chunk = a1 ? (int)blockIdx.x - nchunk : (int)blockIdx.x;
    const int*   __restrict__ rows  = a1 ? rows1  : rows0;
    const int*   __restrict__ cols  = a1 ? cols1  : cols0;
    const float* __restrict__ vals  = a1 ? vals1  : vals0;
    int*         __restrict__ bkcur = a1 ? bkcur1 : bkcur0;
    int2*        __restrict__ binned= a1 ? binned1: binned0;

    __shared__ int lcnt[NBK_MAX];
    __shared__ int lstart[NBK_MAX];
    __shared__ int lbase[NBK_MAX];
    __shared__ int lofs[NBK_MAX];
    __shared__ int smeta[C_CHUNK];
    __shared__ int sval[C_CHUNK];
    __shared__ unsigned short sbucket[C_CHUNK];

    const int tid = threadIdx.x;
    const int e0 = chunk * C_CHUNK;
    const int m = min(C_CHUNK, E - e0);

    lcnt[tid] = 0;
    __syncthreads();

    int rr[C_EPT];
#pragma unroll
    for (int k = 0; k < C_EPT; ++k) {
        const int j = tid + k * 512;
        rr[k] = (j < m) ? rows[e0 + j] : -1;
        if (rr[k] >= 0) atomicAdd(&lcnt[rr[k] >> 8], 1);
    }
    __syncthreads();

    // exclusive scan over 512 buckets (Hillis-Steele)
    const int own = lcnt[tid];
    lstart[tid] = own;
    __syncthreads();
    int val = own;
    for (int off = 1; off < 512; off <<= 1) {
        const int y = (tid >= off) ? lstart[tid - off] : 0;
        __syncthreads();
        val += y;
        lstart[tid] = val;
        __syncthreads();
    }
    const int excl = val - own;
    lstart[tid] = excl;
    if (own > 0) lbase[tid] = atomicAdd(&bkcur[tid], own);
    lofs[tid] = excl;
    __syncthreads();

    // stage records into LDS in bucket-sorted order; memoize bucket per slot
#pragma unroll
    for (int k = 0; k < C_EPT; ++k) {
        const int j = tid + k * 512;
        if (j < m) {
            const int r = rr[k];
            const int b = r >> 8;
            const int slot = atomicAdd(&lofs[b], 1);
            smeta[slot] = ((r & 255) << 24) | cols[e0 + j];
            sval[slot]  = __float_as_int(vals[e0 + j]);
            sbucket[slot] = (unsigned short)b;
        }
    }
    __syncthreads();

    // flush: consecutive threads write consecutive addresses within bucket runs
#pragma unroll
    for (int k = 0; k < C_EPT; ++k) {
        const int j = tid + k * 512;
        if (j < m) {
            const int b = sbucket[j];
            binned[lbase[b] + (j - lstart[b])] = make_int2(smeta[j], sval[j]);
        }
    }
}

// ---------------------------------------------------------------------------
// bucket_to_csr: WG per bucket. Register-caches the bucket's records (single
// global read), local 256-row histogram + scan (which IS the CSR row-start
// array for these rows -> writes rs), LDS reorder, fully sequential flush.
// ---------------------------------------------------------------------------
__global__ __launch_bounds__(256) void bucket_to_csr(
    const int2* __restrict__ binned0, const int2* __restrict__ binned1,
    const int* __restrict__ bbase0, const int* __restrict__ bbase1,
    int* __restrict__ rs0, int* __restrict__ rs1,
    int2* __restrict__ edgep0, int2* __restrict__ edgep1,
    int N, int E, int nbk)
{
    const bool a1 = (int)blockIdx.x >= nbk;
    const int b = a1 ? (int)blockIdx.x - nbk : (int)blockIdx.x;
    const int2* __restrict__ binned = a1 ? binned1 : binned0;
    const int*  __restrict__ bbase  = a1 ? bbase1  : bbase0;
    int*        __restrict__ rs     = a1 ? rs1     : rs0;
    int2*       __restrict__ edgep  = a1 ? edgep1  : edgep0;

    const int r0 = b << 8;
    const int r1 = min(r0 + 256, N);
    const int segbase = bbase[b];
    const int cnt = bbase[b + 1] - segbase;

    __shared__ int lhist[256];
    __shared__ int lstartD[256];
    __shared__ int smeta[DCAP];
    __shared__ int sval[DCAP];

    const int tid = threadIdx.x;
    lhist[tid] = 0;
    __syncthreads();

    if (b == nbk - 1 && tid == 0) rs[N] = E;

    if (cnt <= DCAP) {
        int2 rec[24];                       // DCAP/256 = 24; static unroll only
#pragma unroll
        for (int k = 0; k < 24; ++k) {
            const int j = tid + k * 256;
            if (j < cnt) {
                rec[k] = binned[segbase + j];
                atomicAdd(&lhist[((unsigned)rec[k].x) >> 24], 1);
            }
        }
        __syncthreads();
        const int own = lhist[tid];
        lstartD[tid] = own;
        __syncthreads();
        int val = own;
        for (int off = 1; off < 256; off <<= 1) {
            const int y = (tid >= off) ? lstartD[tid - off] : 0;
            __syncthreads();
            val += y;
            lstartD[tid] = val;
            __syncthreads();
        }
        const int excl = val - own;
        if (r0 + tid < r1) rs[r0 + tid] = segbase + excl;   // CSR row starts
        lstartD[tid] = excl;                                // reuse as cursors
        __syncthreads();
#pragma unroll
        for (int k = 0; k < 24; ++k) {
            const int j = tid + k * 256;
            if (j < cnt) {
                const int lrow = ((unsigned)rec[k].x) >> 24;
                const int slot = atomicAdd(&lstartD[lrow], 1);
                smeta[slot] = rec[k].x & 0xFFFFFF;
                sval[slot]  = rec[k].y;
            }
        }
        __syncthreads();
        for (int j = tid; j < cnt; j += 256)
            edgep[segbase + j] = make_int2(smeta[j], sval[j]);
    } else {
        // statistically unreachable overflow; two-pass global, direct scatter
        for (int j = tid; j < cnt; j += 256)
            atomicAdd(&lhist[((unsigned)binned[segbase + j].x) >> 24], 1);
        __syncthreads();
        const int own = lhist[tid];
        lstartD[tid] = own;
        __syncthreads();
        int val = own;
        for (int off = 1; off < 256; off <<= 1) {
            const int y = (tid >= off) ? lstartD[tid - off] : 0;
            __syncthreads();
            val += y;
            lstartD[tid] = val;
            __syncthreads();
        }
        const int excl = val - own;
        if (r0 + tid < r1) rs[r0 + tid] = segbase + excl;
        lstartD[tid] = excl;
        __syncthreads();
        for (int j = tid; j < cnt; j += 256) {
            const int2 rec = binned[segbase + j];
            const int lrow = ((unsigned)rec.x) >> 24;
            const int slot = atomicAdd(&lstartD[lrow], 1);
            edgep[segbase + slot] = make_int2(rec.x & 0xFFFFFF, rec.y);
        }
    }
}

// ---------------------------------------------------------------------------
// SpMM: one wave per output row; two 32-lane halves take alternating edges;
// each lane gathers float4 (16B). 4-deep unroll -> 8 gathers in flight/wave.
// ---------------------------------------------------------------------------
__global__ __launch_bounds__(256) void spmm_csr(
    const float* __restrict__ S1, const float* __restrict__ S2,
    const int* __restrict__ rs0, const int2* __restrict__ edgep0,
    const int* __restrict__ rs1, const int2* __restrict__ edgep1,
    const float* __restrict__ bias, float* __restrict__ out, int N)
{
    const int row = blockIdx.x * 4 + (threadIdx.x >> 6);
    if (row >= N) return;
    const int lane = threadIdx.x & 63;
    const int half = lane >> 5;       // 0: even edges, 1: odd edges
    const int c4 = (lane & 31) * 4;   // this lane's 4 columns

    float4 acc = make_float4(0.f, 0.f, 0.f, 0.f);

#pragma unroll
    for (int adj = 0; adj < 2; ++adj) {
        const float* __restrict__ S     = adj ? S2     : S1;
        const int*   __restrict__ rs    = adj ? rs1    : rs0;
        const int2*  __restrict__ edgep = adj ? edgep1 : edgep0;

        const int e = rs[row + 1];
        int i = rs[row] + half;
        for (; i + 6 < e; i += 8) {
            const int2 e0 = edgep[i];
            const int2 e1 = edgep[i + 2];
            const int2 e2 = edgep[i + 4];
            const int2 e3 = edgep[i + 6];
            const float4 x0 = *(const float4*)&S[(size_t)e0.x * D + c4];
            const float4 x1 = *(const float4*)&S[(size_t)e1.x * D + c4];
            const float4 x2 = *(const float4*)&S[(size_t)e2.x * D + c4];
            const float4 x3 = *(const float4*)&S[(size_t)e3.x * D + c4];
            const float v0 = __int_as_float(e0.y), v1 = __int_as_float(e1.y);
            const float v2 = __int_as_float(e2.y), v3 = __int_as_float(e3.y);
            acc.x = fmaf(v0, x0.x, acc.x); acc.y = fmaf(v0, x0.y, acc.y);
            acc.z = fmaf(v0, x0.z, acc.z); acc.w = fmaf(v0, x0.w, acc.w);
            acc.x = fmaf(v1, x1.x, acc.x); acc.y = fmaf(v1, x1.y, acc.y);
            acc.z = fmaf(v1, x1.z, acc.z); acc.w = fmaf(v1, x1.w, acc.w);
            acc.x = fmaf(v2, x2.x, acc.x); acc.y = fmaf(v2, x2.y, acc.y);
            acc.z = fmaf(v2, x2.z, acc.z); acc.w = fmaf(v2, x2.w, acc.w);
            acc.x = fmaf(v3, x3.x, acc.x); acc.y = fmaf(v3, x3.y, acc.y);
            acc.z = fmaf(v3, x3.z, acc.z); acc.w = fmaf(v3, x3.w, acc.w);
        }
        for (; i + 2 < e; i += 4) {
            const int2 e0 = edgep[i];
            const int2 e1 = edgep[i + 2];
            const float4 x0 = *(const float4*)&S[(size_t)e0.x * D + c4];
            const float4 x1 = *(const float4*)&S[(size_t)e1.x * D + c4];
            const float v0 = __int_as_float(e0.y), v1 = __int_as_float(e1.y);
            acc.x = fmaf(v0, x0.x, acc.x); acc.y = fmaf(v0, x0.y, acc.y);
            acc.z = fmaf(v0, x0.z, acc.z); acc.w = fmaf(v0, x0.w, acc.w);
            acc.x = fmaf(v1, x1.x, acc.x); acc.y = fmaf(v1, x1.y, acc.y);
            acc.z = fmaf(v1, x1.z, acc.z); acc.w = fmaf(v1, x1.w, acc.w);
        }
        for (; i < e; i += 2) {
            const int2 e0 = edgep[i];
            const float v = __int_as_float(e0.y);
            const float4 x = *(const float4*)&S[(size_t)e0.x * D + c4];
            acc.x = fmaf(v, x.x, acc.x); acc.y = fmaf(v, x.y, acc.y);
            acc.z = fmaf(v, x.z, acc.z); acc.w = fmaf(v, x.w, acc.w);
        }
    }

    acc.x += __shfl(acc.x, lane ^ 32);
    acc.y += __shfl(acc.y, lane ^ 32);
    acc.z += __shfl(acc.z, lane ^ 32);
    acc.w += __shfl(acc.w, lane ^ 32);

    if (half == 0) {
        const float4 b = *(const float4*)&bias[c4];
        acc.x += b.x; acc.y += b.y; acc.z += b.z; acc.w += b.w;
        *(float4*)&out[(size_t)row * D + c4] = acc;
    }
}

// ---------------------------------------------------------------------------
// Fallback (ws too small / N too big): init out with bias, atomic scatter.
// ---------------------------------------------------------------------------
__global__ void init_out(const float* __restrict__ bias, float* __restrict__ out, int total)
{
    int i = blockIdx.x * blockDim.x + threadIdx.x;
    if (i < total) out[i] = bias[i & (D - 1)];
}

__global__ __launch_bounds__(256) void spmm_atomic(const float* __restrict__ S,
    const int* __restrict__ rows, const int* __restrict__ cols,
    const float* __restrict__ vals, float* __restrict__ out, int E)
{
    const int e = blockIdx.x * 4 + (threadIdx.x >> 6);
    const int lane = threadIdx.x & 63;
    if (e >= E) return;
    const int r = rows[e], c = cols[e];
    const float v = vals[e];
    const float2 x = *(const float2*)&S[(size_t)c * D + lane * 2];
    atomicAdd(&out[(size_t)r * D + lane * 2 + 0], v * x.x);
    atomicAdd(&out[(size_t)r * D + lane * 2 + 1], v * x.y);
}

// ---------------------------------------------------------------------------
extern "C" void kernel_launch(void* const* d_in, const int* in_sizes, int n_in,
                              void* d_out, int out_size, void* d_ws, size_t ws_size,
                              hipStream_t stream)
{
    const float* X     = (const float*)d_in[0];
    const float* W1    = (const float*)d_in[1];
    const float* W2    = (const float*)d_in[2];
    const float* bias  = (const float*)d_in[3];
    const float* vals0 = (const float*)d_in[4];
    const float* vals1 = (const float*)d_in[5];
    const int*   rows0 = (const int*)d_in[6];
    const int*   cols0 = (const int*)d_in[7];
    const int*   rows1 = (const int*)d_in[8];
    const int*   cols1 = (const int*)d_in[9];
    float* out = (float*)d_out;

    const int N = in_sizes[0] / D;
    const int E = in_sizes[4];
    const int nbk = (N + RPB - 1) / RPB;     // row buckets
    const int nchunk = (E + C_CHUNK - 1) / C_CHUNK;

    auto aln = [](size_t x) { return (x + 255) & ~(size_t)255; };
    char* base = (char*)d_ws;
    size_t off = 0;
    float* S1 = (float*)(base + off); off += aln((size_t)N * D * sizeof(float));
    float* S2 = (float*)(base + off); off += aln((size_t)N * D * sizeof(float));
    // binned arrays alias S1/S2 region (dead before gemm_dual runs)
    int2* binned0 = (int2*)S1;
    int2* binned1 = (int2*)S2;
    int* rs0    = (int*)(base + off); off += aln((size_t)(N + 1) * 4);
    int* rs1    = (int*)(base + off); off += aln((size_t)(N + 1) * 4);
    int* bcnt0  = (int*)(base + off); off += aln((size_t)nbk * 4);
    int* bcnt1  = (int*)(base + off); off += aln((size_t)nbk * 4);
    int* bbase0 = (int*)(base + off); off += aln((size_t)(nbk + 1) * 4);
    int* bbase1 = (int*)(base + off); off += aln((size_t)(nbk + 1) * 4);
    int* bkcur0 = (int*)(base + off); off += aln((size_t)nbk * 4);
    int* bkcur1 = (int*)(base + off); off += aln((size_t)nbk * 4);
    int2* edgep0 = (int2*)(base + off); off += aln((size_t)E * 8);
    int2* edgep1 = (int2*)(base + off); off += aln((size_t)E * 8);
    const size_t need_full = off;

    const bool ok = (ws_size >= need_full) && (nbk <= NBK_MAX) &&
                    ((size_t)E * 8 <= (size_t)N * D * sizeof(float));

    if (ok) {
        // Phase A: bucket-sorted CSR build (binned aliases S1/S2)
        zero_bcnt<<<(nbk + 255) / 256, 256, 0, stream>>>(bcnt0, bcnt1, nbk);
        bin_count<<<2 * nchunk, 512, 0, stream>>>(rows0, rows1, bcnt0, bcnt1, E, nchunk);
        bucket_scan<<<2, 512, 0, stream>>>(bcnt0, bcnt1, bbase0, bbase1,
                                           bkcur0, bkcur1, nbk, E);
        bin_edges<<<2 * nchunk, 512, 0, stream>>>(rows0, cols0, vals0,
                                                  rows1, cols1, vals1,
                                                  bkcur0, bkcur1, binned0, binned1,
                                                  E, nchunk);
        bucket_to_csr<<<2 * nbk, 256, 0, stream>>>(binned0, binned1, bbase0, bbase1,
                                                   rs0, rs1, edgep0, edgep1, N, E, nbk);
        // Phase B: dense supports (overwrites binned alias region)
        gemm_dual<<<(N + 63) / 64, 256, 0, stream>>>(X, W1, W2, S1, S2, N);
        // Phase C: gather SpMM, one write per out row
        spmm_csr<<<(N + 3) / 4, 256, 0, stream>>>(S1, S2, rs0, edgep0,
                                                  rs1, edgep1, bias, out, N);
    } else {
        // Fallback: atomic scatter
        gemm_dual<<<(N + 63) / 64, 256, 0, stream>>>(X, W1, W2, S1, S2, N);
        init_out<<<(N * D + 255) / 256, 256, 0, stream>>>(bias, out, N * D);
        spmm_atomic<<<(E + 3) / 4, 256, 0, stream>>>(S1, rows0, cols0, vals0, out, E);
        spmm_atomic<<<(E + 3) / 4, 256, 0, stream>>>(S2, rows1, cols1, vals1, out, E);
    }
}

// Round 12
// 385.764 us; speedup vs baseline: 2.0742x; 1.2647x over previous
//
#include <hip/hip_runtime.h>

#define D 128
#define RPB 256          // rows per bucket (bucket = row >> 8, lrow = row & 255)
#define NBK_MAX 512      // bucket-scan width; supports N <= 131072
#define C_EPT 8          // edges per thread in bin kernels (WG=512 -> 4096/chunk)
#define C_CHUNK 4096
#define DCAP 6144        // bucket_to_csr LDS capacity (mean 4096, sd ~64)

typedef __attribute__((ext_vector_type(4))) _Float16 h4;
typedef __attribute__((ext_vector_type(8))) _Float16 h8;

// ---------------------------------------------------------------------------
// Fused dual GEMM: S1 = f16(X @ W1), S2 = f16(X @ W2).  Compute fp32, store f16.
// 64x256 tile, per-thread 8x8. No fp32 MFMA on CDNA4 -> vector ALU.
// ---------------------------------------------------------------------------
__global__ __launch_bounds__(256) void gemm_dual(const float* __restrict__ X,
                                                 const float* __restrict__ W1,
                                                 const float* __restrict__ W2,
                                                 _Float16* __restrict__ S1,
                                                 _Float16* __restrict__ S2, int N)
{
    __shared__ float Xs[16][64];    // transposed: Xs[k][m]
    __shared__ float Ws[16][256];   // Ws[k][n]  (n<128 -> W1, n>=128 -> W2)

    const int tid = threadIdx.x;
    const int tx = tid & 31;   // col group 0..31 (4 cols per matrix)
    const int ty = tid >> 5;   // row group 0..7  (8 rows)
    const int row0 = blockIdx.x * 64;

    float acc[8][8];
#pragma unroll
    for (int m = 0; m < 8; ++m)
#pragma unroll
        for (int n = 0; n < 8; ++n) acc[m][n] = 0.f;

    const int xr = tid >> 2;          // 0..63 (row within tile)
    const int xk = (tid & 3) << 2;    // 0,4,8,12 (k offset)
    const int wk = tid >> 4;          // 0..15 (k within tile)
    const int seg = tid & 15;         // 0..15 (16-col segment)
    const float* wsrc = (seg < 8) ? W1 : W2;
    const int wc = (seg & 7) << 4;    // 0..112 source col
    const int wdst = ((seg < 8) ? 0 : 128) + wc;

    for (int k0 = 0; k0 < 128; k0 += 16) {
        float4 xv = make_float4(0.f, 0.f, 0.f, 0.f);
        const int grow = row0 + xr;
        if (grow < N) xv = *(const float4*)&X[(size_t)grow * D + k0 + xk];
        const float* wsp = &wsrc[(size_t)(k0 + wk) * D + wc];
        const float4 w0 = *(const float4*)(wsp + 0);
        const float4 w1 = *(const float4*)(wsp + 4);
        const float4 w2 = *(const float4*)(wsp + 8);
        const float4 w3 = *(const float4*)(wsp + 12);

        __syncthreads();
        Xs[xk + 0][xr] = xv.x;
        Xs[xk + 1][xr] = xv.y;
        Xs[xk + 2][xr] = xv.z;
        Xs[xk + 3][xr] = xv.w;
        *(float4*)&Ws[wk][wdst + 0]  = w0;
        *(float4*)&Ws[wk][wdst + 4]  = w1;
        *(float4*)&Ws[wk][wdst + 8]  = w2;
        *(float4*)&Ws[wk][wdst + 12] = w3;
        __syncthreads();

#pragma unroll
        for (int k = 0; k < 16; ++k) {
            const float4 a0 = *(const float4*)&Xs[k][ty * 8];
            const float4 a1 = *(const float4*)&Xs[k][ty * 8 + 4];
            const float4 b0 = *(const float4*)&Ws[k][tx * 4];
            const float4 b1 = *(const float4*)&Ws[k][128 + tx * 4];
            const float am[8] = {a0.x, a0.y, a0.z, a0.w, a1.x, a1.y, a1.z, a1.w};
            const float bn[8] = {b0.x, b0.y, b0.z, b0.w, b1.x, b1.y, b1.z, b1.w};
#pragma unroll
            for (int m = 0; m < 8; ++m)
#pragma unroll
                for (int n = 0; n < 8; ++n)
                    acc[m][n] = fmaf(am[m], bn[n], acc[m][n]);
        }
    }

    const int c0 = tx * 4;
#pragma unroll
    for (int m = 0; m < 8; ++m) {
        const int r = row0 + ty * 8 + m;
        if (r < N) {
            h4 o1, o2;
#pragma unroll
            for (int j = 0; j < 4; ++j) {
                o1[j] = (_Float16)acc[m][j];
                o2[j] = (_Float16)acc[m][4 + j];
            }
            *(h4*)&S1[(size_t)r * D + c0] = o1;
            *(h4*)&S2[(size_t)r * D + c0] = o2;
        }
    }
}

// ---------------------------------------------------------------------------
// Bucket pipeline: zero_bcnt -> bin_count -> bucket_scan -> bin_edges
//                  -> bucket_to_csr (which also emits rs[])
// ---------------------------------------------------------------------------
__global__ void zero_bcnt(int* __restrict__ b0, int* __restrict__ b1, int nbk)
{
    int i = blockIdx.x * blockDim.x + threadIdx.x;
    if (i < nbk) { b0[i] = 0; b1[i] = 0; }
}

// per-WG LDS bucket histogram over a 4096-edge chunk, flush to global bcnt
__global__ __launch_bounds__(512) void bin_count(
    const int* __restrict__ rows0, const int* __restrict__ rows1,
    int* __restrict__ bcnt0, int* __restrict__ bcnt1, int E, int nchunk)
{
    const bool a1 = (int)blockIdx.x >= nchunk;
    const int chunk = a1 ? (int)blockIdx.x - nchunk : (int)blockIdx.x;
    const int* __restrict__ rows = a1 ? rows1 : rows0;
    int* __restrict__ bcnt = a1 ? bcnt1 : bcnt0;

    __shared__ int lcnt[NBK_MAX];
    const int tid = threadIdx.x;
    lcnt[tid] = 0;
    __syncthreads();
    const int e0 = chunk * C_CHUNK;
    const int m = min(C_CHUNK, E - e0);
#pragma unroll
    for (int k = 0; k < C_EPT; ++k) {
        const int j = tid + k * 512;
        if (j < m) atomicAdd(&lcnt[rows[e0 + j] >> 8], 1);
    }
    __syncthreads();
    if (lcnt[tid] > 0) atomicAdd(&bcnt[tid], lcnt[tid]);
}

// exclusive scan over nbk bucket counts (nbk <= 512); grid=2 (one per adj).
// writes bbase[0..nbk] (bbase[nbk]=E) and bkcur = bbase.
__global__ __launch_bounds__(512) void bucket_scan(
    const int* __restrict__ bcnt0, const int* __restrict__ bcnt1,
    int* __restrict__ bbase0, int* __restrict__ bbase1,
    int* __restrict__ bkcur0, int* __restrict__ bkcur1, int nbk, int E)
{
    const bool a1 = blockIdx.x == 1;
    const int* __restrict__ bcnt = a1 ? bcnt1 : bcnt0;
    int* __restrict__ bbase = a1 ? bbase1 : bbase0;
    int* __restrict__ bkcur = a1 ? bkcur1 : bkcur0;

    __shared__ int sh[512];
    const int tid = threadIdx.x;
    const int x = (tid < nbk) ? bcnt[tid] : 0;
    sh[tid] = x;
    __syncthreads();
    int val = x;
    for (int off = 1; off < 512; off <<= 1) {
        const int y = (tid >= off) ? sh[tid - off] : 0;
        __syncthreads();
        val += y;
        sh[tid] = val;
        __syncthreads();
    }
    if (tid < nbk) { bbase[tid] = val - x; bkcur[tid] = val - x; }
    if (tid == 0) bbase[nbk] = E;
}

// ---------------------------------------------------------------------------
// bin_edges: LDS-staged scatter into row-buckets (bucket = row>>8).
// ---------------------------------------------------------------------------
__global__ __launch_bounds__(512) void bin_edges(
    const int* __restrict__ rows0, const int* __restrict__ cols0, const float* __restrict__ vals0,
    const int* __restrict__ rows1, const int* __restrict__ cols1, const float* __restrict__ vals1,
    int* __restrict__ bkcur0, int* __restrict__ bkcur1,
    int2* __restrict__ binned0, int2* __restrict__ binned1,
    int E, int nchunk)
{
    const bool a1 = (int)blockIdx.x >= nchunk;
    const int chunk = a1 ? (int)blockIdx.x - nchunk : (int)blockIdx.x;
    const int*   __restrict__ rows  = a1 ? rows1  : rows0;
    const int*   __restrict__ cols  = a1 ? cols1  : cols0;
    const float* __restrict__ vals  = a1 ? vals1  : vals0;
    int*         __restrict__ bkcur = a1 ? bkcur1 : bkcur0;
    int2*        __restrict__ binned= a1 ? binned1: binned0;

    __shared__ int lcnt[NBK_MAX];
    __shared__ int lstart[NBK_MAX];
    __shared__ int lbase[NBK_MAX];
    __shared__ int lofs[NBK_MAX];
    __shared__ int smeta[C_CHUNK];
    __shared__ int sval[C_CHUNK];
    __shared__ unsigned short sbucket[C_CHUNK];

    const int tid = threadIdx.x;
    const int e0 = chunk * C_CHUNK;
    const int m = min(C_CHUNK, E - e0);

    lcnt[tid] = 0;
    __syncthreads();

    int rr[C_EPT];
#pragma unroll
    for (int k = 0; k < C_EPT; ++k) {
        const int j = tid + k * 512;
        rr[k] = (j < m) ? rows[e0 + j] : -1;
        if (rr[k] >= 0) atomicAdd(&lcnt[rr[k] >> 8], 1);
    }
    __syncthreads();

    const int own = lcnt[tid];
    lstart[tid] = own;
    __syncthreads();
    int val = own;
    for (int off = 1; off < 512; off <<= 1) {
        const int y = (tid >= off) ? lstart[tid - off] : 0;
        __syncthreads();
        val += y;
        lstart[tid] = val;
        __syncthreads();
    }
    const int excl = val - own;
    lstart[tid] = excl;
    if (own > 0) lbase[tid] = atomicAdd(&bkcur[tid], own);
    lofs[tid] = excl;
    __syncthreads();

#pragma unroll
    for (int k = 0; k < C_EPT; ++k) {
        const int j = tid + k * 512;
        if (j < m) {
            const int r = rr[k];
            const int b = r >> 8;
            const int slot = atomicAdd(&lofs[b], 1);
            smeta[slot] = ((r & 255) << 24) | cols[e0 + j];
            sval[slot]  = __float_as_int(vals[e0 + j]);
            sbucket[slot] = (unsigned short)b;
        }
    }
    __syncthreads();

#pragma unroll
    for (int k = 0; k < C_EPT; ++k) {
        const int j = tid + k * 512;
        if (j < m) {
            const int b = sbucket[j];
            binned[lbase[b] + (j - lstart[b])] = make_int2(smeta[j], sval[j]);
        }
    }
}

// ---------------------------------------------------------------------------
// bucket_to_csr: WG per bucket; register-cached records, LDS sort, writes rs.
// ---------------------------------------------------------------------------
__global__ __launch_bounds__(256) void bucket_to_csr(
    const int2* __restrict__ binned0, const int2* __restrict__ binned1,
    const int* __restrict__ bbase0, const int* __restrict__ bbase1,
    int* __restrict__ rs0, int* __restrict__ rs1,
    int2* __restrict__ edgep0, int2* __restrict__ edgep1,
    int N, int E, int nbk)
{
    const bool a1 = (int)blockIdx.x >= nbk;
    const int b = a1 ? (int)blockIdx.x - nbk : (int)blockIdx.x;
    const int2* __restrict__ binned = a1 ? binned1 : binned0;
    const int*  __restrict__ bbase  = a1 ? bbase1  : bbase0;
    int*        __restrict__ rs     = a1 ? rs1     : rs0;
    int2*       __restrict__ edgep  = a1 ? edgep1  : edgep0;

    const int r0 = b << 8;
    const int r1 = min(r0 + 256, N);
    const int segbase = bbase[b];
    const int cnt = bbase[b + 1] - segbase;

    __shared__ int lhist[256];
    __shared__ int lstartD[256];
    __shared__ int smeta[DCAP];
    __shared__ int sval[DCAP];

    const int tid = threadIdx.x;
    lhist[tid] = 0;
    __syncthreads();

    if (b == nbk - 1 && tid == 0) rs[N] = E;

    if (cnt <= DCAP) {
        int2 rec[24];                       // DCAP/256 = 24; static unroll only
#pragma unroll
        for (int k = 0; k < 24; ++k) {
            const int j = tid + k * 256;
            if (j < cnt) {
                rec[k] = binned[segbase + j];
                atomicAdd(&lhist[((unsigned)rec[k].x) >> 24], 1);
            }
        }
        __syncthreads();
        const int own = lhist[tid];
        lstartD[tid] = own;
        __syncthreads();
        int val = own;
        for (int off = 1; off < 256; off <<= 1) {
            const int y = (tid >= off) ? lstartD[tid - off] : 0;
            __syncthreads();
            val += y;
            lstartD[tid] = val;
            __syncthreads();
        }
        const int excl = val - own;
        if (r0 + tid < r1) rs[r0 + tid] = segbase + excl;   // CSR row starts
        lstartD[tid] = excl;                                // reuse as cursors
        __syncthreads();
#pragma unroll
        for (int k = 0; k < 24; ++k) {
            const int j = tid + k * 256;
            if (j < cnt) {
                const int lrow = ((unsigned)rec[k].x) >> 24;
                const int slot = atomicAdd(&lstartD[lrow], 1);
                smeta[slot] = rec[k].x & 0xFFFFFF;
                sval[slot]  = rec[k].y;
            }
        }
        __syncthreads();
        for (int j = tid; j < cnt; j += 256)
            edgep[segbase + j] = make_int2(smeta[j], sval[j]);
    } else {
        for (int j = tid; j < cnt; j += 256)
            atomicAdd(&lhist[((unsigned)binned[segbase + j].x) >> 24], 1);
        __syncthreads();
        const int own = lhist[tid];
        lstartD[tid] = own;
        __syncthreads();
        int val = own;
        for (int off = 1; off < 256; off <<= 1) {
            const int y = (tid >= off) ? lstartD[tid - off] : 0;
            __syncthreads();
            val += y;
            lstartD[tid] = val;
            __syncthreads();
        }
        const int excl = val - own;
        if (r0 + tid < r1) rs[r0 + tid] = segbase + excl;
        lstartD[tid] = excl;
        __syncthreads();
        for (int j = tid; j < cnt; j += 256) {
            const int2 rec = binned[segbase + j];
            const int lrow = ((unsigned)rec.x) >> 24;
            const int slot = atomicAdd(&lstartD[lrow], 1);
            edgep[segbase + slot] = make_int2(rec.x & 0xFFFFFF, rec.y);
        }
    }
}

// ---------------------------------------------------------------------------
// SpMM over f16 supports: one wave per row; FOUR 16-lane quarters take
// edges at stride 4; each lane gathers 8 halfs (16B dwordx4) -> quarter
// covers the 256B row. fp32 accumulate; butterfly (^16,^32) combine; lanes
// 0-15 add bias and write the fp32 row (2x dwordx4 per lane).
// ---------------------------------------------------------------------------
__global__ __launch_bounds__(256) void spmm_csr(
    const _Float16* __restrict__ S1, const _Float16* __restrict__ S2,
    const int* __restrict__ rs0, const int2* __restrict__ edgep0,
    const int* __restrict__ rs1, const int2* __restrict__ edgep1,
    const float* __restrict__ bias, float* __restrict__ out, int N)
{
    const int row = blockIdx.x * 4 + (threadIdx.x >> 6);
    if (row >= N) return;
    const int lane = threadIdx.x & 63;
    const int q = lane >> 4;          // quarter 0..3: edges i = start+q, +4...
    const int c8 = (lane & 15) * 8;   // this lane's 8 columns

    float acc[8];
#pragma unroll
    for (int j = 0; j < 8; ++j) acc[j] = 0.f;

#pragma unroll
    for (int adj = 0; adj < 2; ++adj) {
        const _Float16* __restrict__ S  = adj ? S2     : S1;
        const int*   __restrict__ rs    = adj ? rs1    : rs0;
        const int2*  __restrict__ edgep = adj ? edgep1 : edgep0;

        const int e = rs[row + 1];
        int i = rs[row] + q;
        // 2-deep: edges i, i+4 both valid for this quarter
        for (; i + 4 < e; i += 8) {
            const int2 e0 = edgep[i];
            const int2 e1 = edgep[i + 4];
            const h8 x0 = *(const h8*)&S[(size_t)e0.x * D + c8];
            const h8 x1 = *(const h8*)&S[(size_t)e1.x * D + c8];
            const float v0 = __int_as_float(e0.y);
            const float v1 = __int_as_float(e1.y);
#pragma unroll
            for (int j = 0; j < 8; ++j) acc[j] = fmaf(v0, (float)x0[j], acc[j]);
#pragma unroll
            for (int j = 0; j < 8; ++j) acc[j] = fmaf(v1, (float)x1[j], acc[j]);
        }
        // tail singles
        for (; i < e; i += 4) {
            const int2 e0 = edgep[i];
            const h8 x0 = *(const h8*)&S[(size_t)e0.x * D + c8];
            const float v0 = __int_as_float(e0.y);
#pragma unroll
            for (int j = 0; j < 8; ++j) acc[j] = fmaf(v0, (float)x0[j], acc[j]);
        }
    }

    // combine quarters (each holds partial sums for the SAME 8 cols)
#pragma unroll
    for (int j = 0; j < 8; ++j) {
        acc[j] += __shfl(acc[j], lane ^ 16);
        acc[j] += __shfl(acc[j], lane ^ 32);
    }

    if (q == 0) {
        const float4 b0 = *(const float4*)&bias[c8];
        const float4 b1 = *(const float4*)&bias[c8 + 4];
        float* o = &out[(size_t)row * D + c8];
        *(float4*)o       = make_float4(acc[0] + b0.x, acc[1] + b0.y,
                                        acc[2] + b0.z, acc[3] + b0.w);
        *(float4*)(o + 4) = make_float4(acc[4] + b1.x, acc[5] + b1.y,
                                        acc[6] + b1.z, acc[7] + b1.w);
    }
}

// ---------------------------------------------------------------------------
// Fallback (ws too small / N too big): init out with bias, atomic scatter.
// ---------------------------------------------------------------------------
__global__ void init_out(const float* __restrict__ bias, float* __restrict__ out, int total)
{
    int i = blockIdx.x * blockDim.x + threadIdx.x;
    if (i < total) out[i] = bias[i & (D - 1)];
}

__global__ __launch_bounds__(256) void spmm_atomic(const _Float16* __restrict__ S,
    const int* __restrict__ rows, const int* __restrict__ cols,
    const float* __restrict__ vals, float* __restrict__ out, int E)
{
    const int e = blockIdx.x * 4 + (threadIdx.x >> 6);
    const int lane = threadIdx.x & 63;
    if (e >= E) return;
    const int r = rows[e], c = cols[e];
    const float v = vals[e];
    const _Float16 x0 = S[(size_t)c * D + lane * 2];
    const _Float16 x1 = S[(size_t)c * D + lane * 2 + 1];
    atomicAdd(&out[(size_t)r * D + lane * 2 + 0], v * (float)x0);
    atomicAdd(&out[(size_t)r * D + lane * 2 + 1], v * (float)x1);
}

// ---------------------------------------------------------------------------
extern "C" void kernel_launch(void* const* d_in, const int* in_sizes, int n_in,
                              void* d_out, int out_size, void* d_ws, size_t ws_size,
                              hipStream_t stream)
{
    const float* X     = (const float*)d_in[0];
    const float* W1    = (const float*)d_in[1];
    const float* W2    = (const float*)d_in[2];
    const float* bias  = (const float*)d_in[3];
    const float* vals0 = (const float*)d_in[4];
    const float* vals1 = (const float*)d_in[5];
    const int*   rows0 = (const int*)d_in[6];
    const int*   cols0 = (const int*)d_in[7];
    const int*   rows1 = (const int*)d_in[8];
    const int*   cols1 = (const int*)d_in[9];
    float* out = (float*)d_out;

    const int N = in_sizes[0] / D;
    const int E = in_sizes[4];
    const int nbk = (N + RPB - 1) / RPB;     // row buckets
    const int nchunk = (E + C_CHUNK - 1) / C_CHUNK;

    auto aln = [](size_t x) { return (x + 255) & ~(size_t)255; };
    char* base = (char*)d_ws;
    size_t off = 0;
    _Float16* S1 = (_Float16*)(base + off); off += aln((size_t)N * D * sizeof(_Float16));
    _Float16* S2 = (_Float16*)(base + off); off += aln((size_t)N * D * sizeof(_Float16));
    // binned arrays alias S1/S2 region (dead before gemm_dual runs)
    int2* binned0 = (int2*)S1;
    int2* binned1 = (int2*)S2;
    int* rs0    = (int*)(base + off); off += aln((size_t)(N + 1) * 4);
    int* rs1    = (int*)(base + off); off += aln((size_t)(N + 1) * 4);
    int* bcnt0  = (int*)(base + off); off += aln((size_t)nbk * 4);
    int* bcnt1  = (int*)(base + off); off += aln((size_t)nbk * 4);
    int* bbase0 = (int*)(base + off); off += aln((size_t)(nbk + 1) * 4);
    int* bbase1 = (int*)(base + off); off += aln((size_t)(nbk + 1) * 4);
    int* bkcur0 = (int*)(base + off); off += aln((size_t)nbk * 4);
    int* bkcur1 = (int*)(base + off); off += aln((size_t)nbk * 4);
    int2* edgep0 = (int2*)(base + off); off += aln((size_t)E * 8);
    int2* edgep1 = (int2*)(base + off); off += aln((size_t)E * 8);
    const size_t need_full = off;

    const bool ok = (ws_size >= need_full) && (nbk <= NBK_MAX) &&
                    ((size_t)E * 8 <= (size_t)N * D * sizeof(_Float16));

    if (ok) {
        // Phase A: bucket-sorted CSR build (binned aliases S1/S2)
        zero_bcnt<<<(nbk + 255) / 256, 256, 0, stream>>>(bcnt0, bcnt1, nbk);
        bin_count<<<2 * nchunk, 512, 0, stream>>>(rows0, rows1, bcnt0, bcnt1, E, nchunk);
        bucket_scan<<<2, 512, 0, stream>>>(bcnt0, bcnt1, bbase0, bbase1,
                                           bkcur0, bkcur1, nbk, E);
        bin_edges<<<2 * nchunk, 512, 0, stream>>>(rows0, cols0, vals0,
                                                  rows1, cols1, vals1,
                                                  bkcur0, bkcur1, binned0, binned1,
                                                  E, nchunk);
        bucket_to_csr<<<2 * nbk, 256, 0, stream>>>(binned0, binned1, bbase0, bbase1,
                                                   rs0, rs1, edgep0, edgep1, N, E, nbk);
        // Phase B: dense supports (overwrites binned alias region)
        gemm_dual<<<(N + 63) / 64, 256, 0, stream>>>(X, W1, W2, S1, S2, N);
        // Phase C: gather SpMM, one write per out row
        spmm_csr<<<(N + 3) / 4, 256, 0, stream>>>(S1, S2, rs0, edgep0,
                                                  rs1, edgep1, bias, out, N);
    } else {
        // Fallback: atomic scatter
        gemm_dual<<<(N + 63) / 64, 256, 0, stream>>>(X, W1, W2, S1, S2, N);
        init_out<<<(N * D + 255) / 256, 256, 0, stream>>>(bias, out, N * D);
        spmm_atomic<<<(E + 3) / 4, 256, 0, stream>>>(S1, rows0, cols0, vals0, out, E);
        spmm_atomic<<<(E + 3) / 4, 256, 0, stream>>>(S2, rows1, cols1, vals1, out, E);
    }
}